// Round 11
// baseline (151.793 us; speedup 1.0000x reference)
//
#include <hip/hip_runtime.h>
#include <hip/hip_bf16.h>
#include <math.h>

// Cart2Polar: output[b,c,y,x] = bilinear_sample(grid_feat[b,c], gx(y,x), gy(y,x))
// ref_feat is fully overwritten by the reference's scatter -> unused.
// Shapes (fixed): grid_feat [4,64,480,480] f32, out [4,64,480,360] f32.
//
// R11 = R10 + theta-wedge XCD chunking. R8's identity map makes every XCD
// stream the ENTIRE 236MB input through its private L2 (8x236MB = 1.9GB of
// L3 traffic = ~14TB/s = the wall). Chunking along THETA (xt slowest, each
// XCD owns a contiguous ~2.9-column wedge) cuts per-XCD footprint to ~31MB
// -> ~6x less L3 traffic. Unlike R7's radius-chunking, every xt column
// contains ALL radii -> per-XCD work is identical -> balance preserved.

#define BB 4
#define CC 64
#define HC 480
#define WC 480
#define HP 480
#define WP 360

#define TY 16
#define TX 16
#define BYT (HP / TY)                  // 30
#define BXT ((WP + TX - 1) / TX)       // 23 (last tile x>=360 lanes: computed, not stored)
#define CSPLIT 4
#define CCB (CC / CSPLIT)              // 16 channels per block
#define NWG (BB * BYT * BXT * CSPLIT)  // 11040
#define NXCD 8
#define CPX (NWG / NXCD)               // 1380
#define CB 16                          // = CCB, single LDS batch

typedef float f2a __attribute__((ext_vector_type(2), aligned(8)));

__global__ __launch_bounds__(256, 2) void c2p_kernel(const float* __restrict__ g,
                                                     float* __restrict__ out) {
    __shared__ float lds[CB][TY][TX + 1];   // +1 pad: conflict-free scalar r/w

    // --- theta-wedge XCD chunking ---
    // physical bid -> xcd = bid%8 (HW round-robin), slot = bid/8
    // logical order: h fastest, then b, then yt, then xt SLOWEST
    // -> XCD k owns logical [k*1380, (k+1)*1380) = a contiguous theta wedge
    //    (~2.9 xt columns, all radii, all batches, all channel-quarters).
    const int bid = blockIdx.x;
    const int logical = (bid & (NXCD - 1)) * CPX + (bid >> 3);
    const int h  = logical % CSPLIT;
    int tmp = logical / CSPLIT;
    const int b  = tmp % BB;
    tmp /= BB;
    const int yt = tmp % BYT;
    const int xt = tmp / BYT;              // slowest: contiguous per XCD

    const int tid  = threadIdx.x;
    const int lane = tid & 63;
    const int w    = tid >> 6;
    // gather-phase mapping: wave = 16 consecutive y (radii) x 4 consecutive x
    const int ly = lane >> 2;                 // 0..15
    const int lx = (w << 2) | (lane & 3);     // 0..15
    const int y  = yt * TY + ly;
    const int x  = xt * TX + lx;              // may be >=360 in last tile (not stored)

    // polar grid math (matches reference, fp32)
    const float PI = 3.14159265358979323846f;
    float theta = PI - (float)x * (2.0f * PI / (float)WP);
    float r = ((float)HP - 0.5f - (float)y + 3.0f) * (1.0f / ((float)HP + 3.0f)) * ((float)WC * 0.5f);
    float s, c;
    __sincosf(theta, &s, &c);
    float index_x = r * c + (float)WC * 0.5f;
    float index_y = r * s + (float)WC * 0.5f;
    const float scale = (float)(WC - 1) / (float)WC;
    float gx = index_x * scale;
    float gy = index_y * scale;

    float x0f = floorf(gx);
    float y0f = floorf(gy);
    float wx1 = gx - x0f;
    float wy1 = gy - y0f;
    float wx0 = 1.0f - wx1;
    float wy0 = 1.0f - wy1;

    // proven in-bounds for this geometry: x0,y0 in [0,478] -> no clamp/validity
    const int x0 = (int)x0f;
    const int y0 = (int)y0f;

    const float w00 = wx0 * wy0;
    const float w10 = wx1 * wy0;
    const float w01 = wx0 * wy1;
    const float w11 = wx1 * wy1;

    const int o0 = y0 * WC + x0;     // row y0, cols (x0, x0+1) as one float2
    const int o1 = o0 + WC;          // row y0+1

    constexpr int HWc = HC * WC;
    constexpr int HWp = HP * WP;

    const float* __restrict__ base = g + ((size_t)b * CC + h * CCB) * HWc;

    // store-phase mapping: x-major, 16 rows x 64B per wave-store
    const int srow = tid >> 4;                // 0..15
    const int scol = tid & 15;                // 0..15
    const int sy = yt * TY + srow;
    const int sx = xt * TX + scol;
    const bool sok = (sx < WP);
    float* __restrict__ ob = out + ((size_t)b * CC + h * CCB) * HWp + (size_t)sy * WP + sx;

    // ---- asm-forced gather cluster: 32 dwordx2 loads, all in flight ----
    f2a a0[CB], a1[CB];
#pragma unroll
    for (int j = 0; j < CB; ++j) {
        const float* p0 = base + (size_t)j * HWc + o0;
        const float* p1 = base + (size_t)j * HWc + o1;
        asm volatile("global_load_dwordx2 %0, %1, off"
                     : "=v"(a0[j]) : "v"(p0));
        asm volatile("global_load_dwordx2 %0, %1, off"
                     : "=v"(a1[j]) : "v"(p1));
    }

    // ---- counted drain: consume channel j while 2*(CB-1-j) loads still fly ----
#pragma unroll
    for (int j = 0; j < CB; ++j) {
        asm volatile("s_waitcnt vmcnt(%0)" :: "i"(2 * (CB - 1 - j)) : "memory");
        __builtin_amdgcn_sched_barrier(0);
        lds[j][ly][lx] = a0[j].x * w00 + a0[j].y * w10
                       + a1[j].x * w01 + a1[j].y * w11;
    }
    __syncthreads();

    if (sok) {
#pragma unroll
        for (int j = 0; j < CB; ++j)
            __builtin_nontemporal_store(lds[j][srow][scol], &ob[(size_t)j * HWp]);
    }
}

extern "C" void kernel_launch(void* const* d_in, const int* in_sizes, int n_in,
                              void* d_out, int out_size, void* d_ws, size_t ws_size,
                              hipStream_t stream) {
    const float* grid_feat = (const float*)d_in[0];
    float* out = (float*)d_out;
    c2p_kernel<<<NWG, 256, 0, stream>>>(grid_feat, out);
}